// Round 9
// baseline (184.736 us; speedup 1.0000x reference)
//
#include <hip/hip_runtime.h>
#include <hip/hip_bf16.h>

#define LL 512
#define BB 32
#define DD 256
#define NS 16
#define RK 16
#define CH4 32         // chunks over L (fused scan)
#define LC4 16         // L per chunk
#define DT4 16         // d-channels per block tile

typedef __attribute__((ext_vector_type(8))) short bf16x8;
typedef __attribute__((ext_vector_type(8))) _Float16 f16x8;
typedef __attribute__((ext_vector_type(4))) float f32x4;

// load 16 consecutive floats into a scalar array (float4 x4)
#define LD16(dst, src, off) { \
  float4 _v0 = *reinterpret_cast<const float4*>(&(src)[(off)]); \
  float4 _v1 = *reinterpret_cast<const float4*>(&(src)[(off)+4]); \
  float4 _v2 = *reinterpret_cast<const float4*>(&(src)[(off)+8]); \
  float4 _v3 = *reinterpret_cast<const float4*>(&(src)[(off)+12]); \
  dst[0]=_v0.x; dst[1]=_v0.y; dst[2]=_v0.z; dst[3]=_v0.w; \
  dst[4]=_v1.x; dst[5]=_v1.y; dst[6]=_v1.z; dst[7]=_v1.w; \
  dst[8]=_v2.x; dst[9]=_v2.y; dst[10]=_v2.z; dst[11]=_v2.w; \
  dst[12]=_v3.x; dst[13]=_v3.y; dst[14]=_v3.z; dst[15]=_v3.w; }

static __device__ __forceinline__ unsigned short f2bf(float x) {
    __hip_bfloat16 h = __float2bfloat16(x);
    return *reinterpret_cast<unsigned short*>(&h);
}

// load 8 consecutive fp32 and convert to f16x8
static __device__ __forceinline__ f16x8 ld_cvt_f16(const float* p) {
    float4 lo = *reinterpret_cast<const float4*>(p);
    float4 hi = *reinterpret_cast<const float4*>(p + 4);
    f16x8 r;
    r[0] = (_Float16)lo.x; r[1] = (_Float16)lo.y; r[2] = (_Float16)lo.z; r[3] = (_Float16)lo.w;
    r[4] = (_Float16)hi.x; r[5] = (_Float16)hi.y; r[6] = (_Float16)hi.z; r[7] = (_Float16)hi.w;
    return r;
}

// ---------------- K0: W -> bf16 ----------------
__global__ __launch_bounds__(256) void k0_wbf(
    const float* __restrict__ W, unsigned short* __restrict__ Wbf)
{
    int i = (blockIdx.x * 256 + threadIdx.x) * 4;
    float4 v = *reinterpret_cast<const float4*>(&W[i]);
    ushort4 o;
    o.x = f2bf(v.x); o.y = f2bf(v.y); o.z = f2bf(v.z); o.w = f2bf(v.w);
    *reinterpret_cast<ushort4*>(&Wbf[i]) = o;
}

// ---------------- K1a: x_dbl = flow @ x_proj_w^T via f16 MFMA ----------------
// M=16384 (row = b*512+l), N=48, K=256.  Block 256 = 4 waves x 16 rows.
__global__ __launch_bounds__(256) void k1a_xdbl(
    const float* __restrict__ flow,       // (L,B,D): row at (l*BB+b)*DD
    const float* __restrict__ x_proj_w,   // (48,D)
    float* __restrict__ xdbl)             // (16384,48)
{
    int wave = threadIdx.x >> 6;
    int lane = threadIdx.x & 63;
    int rl = lane & 15, kb = lane >> 4;
    int arow = blockIdx.x * 64 + wave * 16 + rl;      // A row for this lane
    int b = arow >> 9, l = arow & 511;
    const float* abase = &flow[(l * BB + b) * DD];

    f32x4 acc[3] = {};
    #pragma unroll
    for (int ks = 0; ks < 8; ++ks) {
        int k0 = ks * 32 + kb * 8;
        f16x8 af = ld_cvt_f16(abase + k0);
        #pragma unroll
        for (int j = 0; j < 3; ++j) {
            f16x8 bf = ld_cvt_f16(&x_proj_w[(j * 16 + rl) * DD + k0]);
            acc[j] = __builtin_amdgcn_mfma_f32_16x16x32_f16(af, bf, acc[j], 0, 0, 0);
        }
    }
    // C/D: col = lane&15, row = (lane>>4)*4 + reg
    int row_out = blockIdx.x * 64 + wave * 16 + kb * 4;
    #pragma unroll
    for (int j = 0; j < 3; ++j)
        #pragma unroll
        for (int reg = 0; reg < 4; ++reg)
            xdbl[(size_t)(row_out + reg) * 48 + j * 16 + rl] = acc[j][reg];
}

// ---------------- K1b: delta/B/C from x_dbl ----------------
// block: 32 rows.  stage x_dbl tile to LDS, then B/C copy + delta projection.
__global__ __launch_bounds__(256) void k1b_proj(
    const float* __restrict__ xdbl,       // (16384,48)
    const float* __restrict__ dt_w,       // (D,RK)
    const float* __restrict__ dt_b,       // (D)
    float* __restrict__ delta,            // (B,L,D)
    float* __restrict__ Bm,               // (B,L,NS)
    float* __restrict__ Cm)               // (B,L,NS)
{
    __shared__ float sx[32 * 48];         // 6 KB
    int tid = threadIdx.x;
    int row0 = blockIdx.x * 32;

    // contiguous copy: 1536 floats = 384 float4
    {
        int i4 = tid;
        *reinterpret_cast<float4*>(&sx[i4 * 4]) =
            *reinterpret_cast<const float4*>(&xdbl[(size_t)row0 * 48 + i4 * 4]);
        i4 = tid + 256;
        if (i4 < 384)
            *reinterpret_cast<float4*>(&sx[i4 * 4]) =
                *reinterpret_cast<const float4*>(&xdbl[(size_t)row0 * 48 + i4 * 4]);
    }
    __syncthreads();

    // B/C copy out (coalesced): 512 elems each
    #pragma unroll
    for (int jj = 0; jj < 2; ++jj) {
        int idx = tid + jj * 256;
        int r = idx >> 4, c = idx & 15;
        Bm[(size_t)(row0 + r) * NS + c] = sx[r * 48 + RK + c];
        Cm[(size_t)(row0 + r) * NS + c] = sx[r * 48 + RK + NS + c];
    }

    // delta: thread d = tid, loop 32 rows (sx reads wave-uniform broadcast)
    float wreg[RK];
    #pragma unroll
    for (int k = 0; k < RK; k += 4) {
        float4 v = *reinterpret_cast<const float4*>(&dt_w[tid * RK + k]);
        wreg[k] = v.x; wreg[k + 1] = v.y; wreg[k + 2] = v.z; wreg[k + 3] = v.w;
    }
    float bias = dt_b[tid];
    for (int r = 0; r < 32; ++r) {
        const float* srow = &sx[r * 48];
        float s = bias;
        #pragma unroll
        for (int k = 0; k < RK; ++k) s = fmaf(srow[k], wreg[k], s);
        float sp = fmaxf(s, 0.f) + log1pf(__expf(-fabsf(s)));
        delta[(size_t)(row0 + r) * DD + tid] = sp;
    }
}

// ---------------- K2 fused: chunk scan -> LDS prefix -> re-scan ----------------
// grid: b (32) x d-tile (16);  block 512 = chunk c (32) x channel dl (16)
__global__ __launch_bounds__(512) void k2_fused(
    const float* __restrict__ u_pos,    // (L,B,D)
    const float* __restrict__ h0,       // (B,D,NS)
    const float* __restrict__ A_log,    // (D,NS)
    const float* __restrict__ Dp,       // (D)
    const float* __restrict__ delta,    // (B,L,D)
    const float* __restrict__ Bm,       // (B,L,NS)
    const float* __restrict__ Cm,       // (B,L,NS)
    unsigned short* __restrict__ ybf,   // (B,L,D) bf16
    float* __restrict__ h_out)          // (B,D,NS)
{
    extern __shared__ float smem[];            // 65536 B
    float* lap = smem;                         // [NS][CH4*DT4] = 16 x 512
    float* lhp = smem + NS * CH4 * DT4;

    int tid = threadIdx.x;
    int b  = blockIdx.x >> 4;
    int dt = blockIdx.x & 15;
    int dl = tid & 15, c = tid >> 4;           // dl 0..15, c 0..31
    int d  = dt * DT4 + dl;
    int l0 = c * LC4;

    // per-thread A coefficients (folded log2e)
    float a[NS];
    #pragma unroll
    for (int n = 0; n < NS; n += 4) {
        float4 v = *reinterpret_cast<const float4*>(&A_log[d * NS + n]);
        a[n]     = -__expf(v.x) * 1.44269504f;
        a[n + 1] = -__expf(v.y) * 1.44269504f;
        a[n + 2] = -__expf(v.z) * 1.44269504f;
        a[n + 3] = -__expf(v.w) * 1.44269504f;
    }

    const float* dp = delta + ((size_t)b * LL + l0) * DD + d;
    const float* up = u_pos + ((size_t)l0 * BB + b) * DD + d;
    const float* Bp = Bm + ((size_t)b * LL + l0) * NS;
    const float* Cp = Cm + ((size_t)b * LL + l0) * NS;

    // ---- phase A: local chunk scan from zero ----
    float h[NS], ap[NS];
    #pragma unroll
    for (int n = 0; n < NS; ++n) { h[n] = 0.f; ap[n] = 1.f; }

    for (int l = 0; l < LC4; l += 2) {
        float d0 = dp[l * DD],        d1 = dp[(l + 1) * DD];
        float u0 = up[l * BB * DD],   u1 = up[(l + 1) * BB * DD];
        float B0[NS], B1[NS];
        LD16(B0, Bp, l * NS);
        LD16(B1, Bp, (l + 1) * NS);
        float du0 = d0 * u0, du1 = d1 * u1;
        #pragma unroll
        for (int n = 0; n < NS; ++n) {
            float dA = exp2f(d0 * a[n]);
            ap[n] *= dA;
            h[n] = fmaf(dA, h[n], du0 * B0[n]);
        }
        #pragma unroll
        for (int n = 0; n < NS; ++n) {
            float dA = exp2f(d1 * a[n]);
            ap[n] *= dA;
            h[n] = fmaf(dA, h[n], du1 * B1[n]);
        }
    }
    #pragma unroll
    for (int n = 0; n < NS; ++n) {
        lap[n * (CH4 * DT4) + c * DT4 + dl] = ap[n];   // lanes consecutive: free
        lhp[n * (CH4 * DT4) + c * DT4 + dl] = h[n];
    }
    __syncthreads();

    // ---- phase B: sequential prefix over 32 chunks (256 threads: (dl2, n2)) ----
    if (tid < DT4 * NS) {
        int dl2 = tid & 15, n2 = tid >> 4;
        float s = h0[((size_t)b * DD + dt * DT4 + dl2) * NS + n2];
        #pragma unroll 4
        for (int c2 = 0; c2 < CH4; ++c2) {
            int idx = n2 * (CH4 * DT4) + c2 * DT4 + dl2;
            float apv = lap[idx];
            float hpv = lhp[idx];
            lap[idx] = s;                  // in-place: becomes h_in for chunk c2
            s = fmaf(apv, s, hpv);
        }
        h_out[((size_t)b * DD + dt * DT4 + dl2) * NS + n2] = s;
    }
    __syncthreads();

    // ---- phase C: re-scan with true h_in, emit y ----
    #pragma unroll
    for (int n = 0; n < NS; ++n)
        h[n] = lap[n * (CH4 * DT4) + c * DT4 + dl];
    float Dd = Dp[d];
    unsigned short* yp = ybf + ((size_t)b * LL + l0) * DD + d;

    for (int l = 0; l < LC4; l += 2) {
        float d0 = dp[l * DD],        d1 = dp[(l + 1) * DD];
        float u0 = up[l * BB * DD],   u1 = up[(l + 1) * BB * DD];
        float B0[NS], B1[NS], C0[NS], C1[NS];
        LD16(B0, Bp, l * NS);
        LD16(B1, Bp, (l + 1) * NS);
        LD16(C0, Cp, l * NS);
        LD16(C1, Cp, (l + 1) * NS);

        float du0 = d0 * u0, du1 = d1 * u1;
        float acc0 = 0.f, acc1 = 0.f;
        #pragma unroll
        for (int n = 0; n < NS; ++n) {
            float dA = exp2f(d0 * a[n]);
            h[n] = fmaf(dA, h[n], du0 * B0[n]);
            acc0 = fmaf(h[n], C0[n], acc0);
        }
        #pragma unroll
        for (int n = 0; n < NS; ++n) {
            float dA = exp2f(d1 * a[n]);
            h[n] = fmaf(dA, h[n], du1 * B1[n]);
            acc1 = fmaf(h[n], C1[n], acc1);
        }
        yp[l * DD]       = f2bf(fmaf(u0, Dd, acc0));
        yp[(l + 1) * DD] = f2bf(fmaf(u1, Dd, acc1));
    }
}

// ---------------- K3: output projection via bf16 MFMA ----------------
// Out(16384,256) = Y @ W^T.  Block 64x128 (grid 512 = 2/CU), wave 32x64.
__global__ __launch_bounds__(256) void k3_mfma(
    const unsigned short* __restrict__ Ybf,   // (16384,256)
    const unsigned short* __restrict__ Wbf,   // (256,256)
    float* __restrict__ Out)
{
    int wave = threadIdx.x >> 6;
    int lane = threadIdx.x & 63;
    int row0 = (blockIdx.x >> 1) * 64 + (wave >> 1) * 32;
    int col0 = (blockIdx.x & 1) * 128 + (wave & 1) * 64;
    int rl = lane & 15, kb = lane >> 4;

    f32x4 acc[2][4] = {};
    bf16x8 af[2], bf[4], afn[2], bfn[4];

    #pragma unroll
    for (int i = 0; i < 2; ++i)
        af[i] = *reinterpret_cast<const bf16x8*>(&Ybf[(size_t)(row0 + i * 16 + rl) * DD + kb * 8]);
    #pragma unroll
    for (int j = 0; j < 4; ++j)
        bf[j] = *reinterpret_cast<const bf16x8*>(&Wbf[(size_t)(col0 + j * 16 + rl) * DD + kb * 8]);

    #pragma unroll
    for (int ks = 0; ks < 8; ++ks) {
        int kn = (ks + 1) * 32 + kb * 8;
        if (ks < 7) {
            #pragma unroll
            for (int i = 0; i < 2; ++i)
                afn[i] = *reinterpret_cast<const bf16x8*>(&Ybf[(size_t)(row0 + i * 16 + rl) * DD + kn]);
            #pragma unroll
            for (int j = 0; j < 4; ++j)
                bfn[j] = *reinterpret_cast<const bf16x8*>(&Wbf[(size_t)(col0 + j * 16 + rl) * DD + kn]);
        }
        #pragma unroll
        for (int i = 0; i < 2; ++i)
            #pragma unroll
            for (int j = 0; j < 4; ++j)
                acc[i][j] = __builtin_amdgcn_mfma_f32_16x16x32_bf16(af[i], bf[j], acc[i][j], 0, 0, 0);
        #pragma unroll
        for (int i = 0; i < 2; ++i) af[i] = afn[i];
        #pragma unroll
        for (int j = 0; j < 4; ++j) bf[j] = bfn[j];
    }

    // C/D: col = lane&15, row = (lane>>4)*4 + reg
    #pragma unroll
    for (int i = 0; i < 2; ++i)
        #pragma unroll
        for (int j = 0; j < 4; ++j)
            #pragma unroll
            for (int reg = 0; reg < 4; ++reg)
                Out[(size_t)(row0 + i * 16 + kb * 4 + reg) * DD + col0 + j * 16 + rl] = acc[i][j][reg];
}

extern "C" void kernel_launch(void* const* d_in, const int* in_sizes, int n_in,
                              void* d_out, int out_size, void* d_ws, size_t ws_size,
                              hipStream_t stream) {
    const float* pos  = (const float*)d_in[0];   // (L,B,D)
    const float* flow = (const float*)d_in[1];   // (L,B,D)
    const float* h0   = (const float*)d_in[2];   // (B,D,NS)
    const float* xw   = (const float*)d_in[3];   // (48,D)
    const float* dtw  = (const float*)d_in[4];   // (D,16)
    const float* dtb  = (const float*)d_in[5];   // (D)
    const float* alog = (const float*)d_in[6];   // (D,NS)
    const float* dpar = (const float*)d_in[7];   // (D)
    const float* ow   = (const float*)d_in[8];   // (256,256)

    float* out = (float*)d_out;                  // out0: 4,194,304 then h_final: 131,072

    float* ws    = (float*)d_ws;
    float* delta = ws;                           // 4,194,304 floats
    float* Bmw   = ws + 4194304;                 //   262,144
    float* Cmw   = ws + 4456448;                 //   262,144
    unsigned short* ybf = (unsigned short*)(ws + 4718592);   // 8 MB
    unsigned short* wbf = (unsigned short*)(ws + 6815744);   // 128 KB
    float* xdbl  = ws + 6848512;                 //   786,432 floats (3 MB)
    // total ws usage: ~30.5 MB

    float* h_out = out + 32 * 512 * 256;

    k0_wbf  <<<64,  256, 0, stream>>>(ow, wbf);
    k1a_xdbl<<<256, 256, 0, stream>>>(flow, xw, xdbl);
    k1b_proj<<<512, 256, 0, stream>>>(xdbl, dtw, dtb, delta, Bmw, Cmw);
    k2_fused<<<512, 512, 65536, stream>>>(pos, h0, alog, dpar, delta, Bmw, Cmw, ybf, h_out);
    k3_mfma <<<512, 256, 0, stream>>>(ybf, wbf, out);
}